// Round 12
// baseline (274.205 us; speedup 1.0000x reference)
//
#include <hip/hip_runtime.h>
#include <hip/hip_bf16.h>

#define VOCAB 64
#define H 64
#define NB 128
#define SL 2048

// ---------------- Kernel A: per-token tables ----------------
__global__ __launch_bounds__(64) void k_tables(
    const float* __restrict__ embed, const float* __restrict__ w1, const float* __restrict__ b1,
    const float* __restrict__ w2, const float* __restrict__ b2,
    const float* __restrict__ ln_g, const float* __restrict__ ln_b,
    const float* __restrict__ Wk, const float* __restrict__ Wv, const float* __restrict__ Wq,
    float* __restrict__ Ktab, float* __restrict__ Vtab, float* __restrict__ qtab)
{
  const int t = blockIdx.x;
  const int i = threadIdx.x;
  __shared__ float h0s[H];
  __shared__ float ff1s[2 * H];
  __shared__ float hs[H];

  h0s[i] = embed[t * H + i];
  __syncthreads();

  const float4* w1v = (const float4*)w1;
  float a0 = b1[i], a1 = b1[i + H];
#pragma unroll
  for (int j4 = 0; j4 < 16; ++j4) {
    const float4 hv = *(const float4*)&h0s[j4 * 4];
    const float4 wa = w1v[i * 16 + j4];
    const float4 wb = w1v[(i + H) * 16 + j4];
    a0 = fmaf(wa.x, hv.x, fmaf(wa.y, hv.y, fmaf(wa.z, hv.z, fmaf(wa.w, hv.w, a0))));
    a1 = fmaf(wb.x, hv.x, fmaf(wb.y, hv.y, fmaf(wb.z, hv.z, fmaf(wb.w, hv.w, a1))));
  }
  ff1s[i] = fmaxf(a0, 0.f);
  ff1s[i + H] = fmaxf(a1, 0.f);
  __syncthreads();

  const float4* w2v = (const float4*)w2;
  float z = h0s[i] + b2[i];
#pragma unroll
  for (int o4 = 0; o4 < 32; ++o4) {
    const float4 fv = *(const float4*)&ff1s[o4 * 4];
    const float4 wv = w2v[i * 32 + o4];
    z = fmaf(wv.x, fv.x, fmaf(wv.y, fv.y, fmaf(wv.z, fv.z, fmaf(wv.w, fv.w, z))));
  }

  float s = z;
#pragma unroll
  for (int m = 1; m < 64; m <<= 1) s += __shfl_xor(s, m);
  const float mu = s * (1.f / 64.f);
  const float d = z - mu;
  float s2 = d * d;
#pragma unroll
  for (int m = 1; m < 64; m <<= 1) s2 += __shfl_xor(s2, m);
  const float var = s2 * (1.f / 64.f);
  const float hv2 = d * rsqrtf(var + 1e-5f) * ln_g[i] + ln_b[i];
  hs[i] = hv2;
  __syncthreads();

  const float4* wkv = (const float4*)Wk;
  const float4* wvv = (const float4*)Wv;
  const float4* wqv = (const float4*)Wq;
  float kk = 0.f, vv = 0.f, qq = 0.f;
#pragma unroll
  for (int j4 = 0; j4 < 16; ++j4) {
    const float4 hj = *(const float4*)&hs[j4 * 4];
    const float4 ak = wkv[i * 16 + j4];
    const float4 av = wvv[i * 16 + j4];
    const float4 aq = wqv[i * 16 + j4];
    kk = fmaf(ak.x, hj.x, fmaf(ak.y, hj.y, fmaf(ak.z, hj.z, fmaf(ak.w, hj.w, kk))));
    vv = fmaf(av.x, hj.x, fmaf(av.y, hj.y, fmaf(av.z, hj.z, fmaf(av.w, hj.w, vv))));
    qq = fmaf(aq.x, hj.x, fmaf(aq.y, hj.y, fmaf(aq.z, hj.z, fmaf(aq.w, hj.w, qq))));
  }
  float n2 = kk * kk;
#pragma unroll
  for (int m = 1; m < 64; m <<= 1) n2 += __shfl_xor(n2, m);
  const float inv = 1.f / fmaxf(sqrtf(n2), 1e-12f);
  Ktab[t * H + i] = kk * inv;
  Vtab[t * H + i] = vv;
  qtab[t * H + i] = qq;
}

// ---------------- Kernel B: Q-cache delta-rule scan ----------------
// State per batch: M (64x64) and Q = M.Ktab^T - V^T. Step with token a:
//   dl_r = -Q[r][a]  (v_readlane);  Q += dl (x) G[a,:];  M += dl (x) K[a,:].
// Decomposition: 4 blocks/batch x 16 rows; block 512 = 8 waves x 2 rows;
// NO launch_bounds occupancy arg: natural ~88 VGPR permits 2 blocks/CU
// (16 waves) without spilling -- round 11's (512,4) forced 64 VGPR and
// spilled the prefetch buffers to scratch (89MB FETCH catastrophe).
__device__ __forceinline__ float rdl(float v, int sl) {
  return __int_as_float(__builtin_amdgcn_readlane(__float_as_int(v), sl));
}

__global__ __launch_bounds__(512) void k_scan(
    const int* __restrict__ x, const float* __restrict__ Ktab, const float* __restrict__ Vtab,
    float* __restrict__ Mout)
{
  const int bb = blockIdx.x >> 2;
  const int quarter = blockIdx.x & 3;
  const int tid = threadIdx.x;   // 0..511
  const int lane = tid & 63;
  const int wave = tid >> 6;     // 0..7
  const int grow = quarter * 16 + wave * 2;  // global row base (2 rows/wave)

  __shared__ float smem[16448];  // 64.25 KB -> 2 blocks/CU
  float* Ks  = smem;             // [64][64]      4096
  float* KTs = smem + 4096;      // [64][65]      4160 (Gram-build scratch)
  float* GKs = smem + 8256;      // [64][64][2]   8192  {G, K} interleaved

  // ---- stage K + K^T ----
#pragma unroll
  for (int u = 0; u < 2; ++u) {
    const int f4i = u * 512 + tid;  // 0..1023 over 64x64
    const float4 kv = ((const float4*)Ktab)[f4i];
    ((float4*)Ks)[f4i] = kv;
    const int row = f4i >> 4, c4 = (f4i & 15) * 4;
    KTs[(c4 + 0) * 65 + row] = kv.x;
    KTs[(c4 + 1) * 65 + row] = kv.y;
    KTs[(c4 + 2) * 65 + row] = kv.z;
    KTs[(c4 + 3) * 65 + row] = kv.w;
  }
  // ---- interleave K into GKs (.y slots) ----
#pragma unroll
  for (int u = 0; u < 8; ++u) {
    const int idx = u * 512 + tid;  // 0..4095
    GKs[idx * 2 + 1] = Ktab[idx];
  }
  __syncthreads();

  // ---- build Gram into GKs (.x slots): wave w computes rows [8w, 8w+8) ----
  {
    const int abase = wave * 8;
#pragma unroll 1
    for (int ar = 0; ar < 8; ++ar) {
      const int a = abase + ar;
      float acc = 0.f;
#pragma unroll
      for (int i = 0; i < H; i += 4) {
        const float4 ka = *(const float4*)&Ks[a * 64 + i];  // uniform broadcast
        acc = fmaf(ka.x, KTs[(i + 0) * 65 + lane], acc);
        acc = fmaf(ka.y, KTs[(i + 1) * 65 + lane], acc);
        acc = fmaf(ka.z, KTs[(i + 2) * 65 + lane], acc);
        acc = fmaf(ka.w, KTs[(i + 3) * 65 + lane], acc);
      }
      GKs[(a * 64 + lane) * 2] = acc;
    }
  }
  __syncthreads();

  // ---- init Q = -V^T slice (P=0), M = 0; one-time global gather ----
  float Q[2], Mr[2];
  Q[0] = -Vtab[lane * H + grow + 0];
  Q[1] = -Vtab[lane * H + grow + 1];
  Mr[0] = 0.f; Mr[1] = 0.f;

  const int* __restrict__ xp = x + bb * SL;  // block-uniform -> scalar loads
  const int lane2 = lane * 2;

  float gA, kA, gB, kB, gC, kC, gD, kD;

#define PREF(G_, K_, a_)                                                   \
  {                                                                        \
    const float2 gk = *(const float2*)&GKs[(a_) * 128 + lane2];            \
    G_ = gk.x; K_ = gk.y;                                                  \
  }

#define STEP(G_, K_, a_)                                                   \
  {                                                                        \
    const float q0 = rdl(Q[0], a_);                                        \
    const float q1 = rdl(Q[1], a_);                                        \
    Q[0] = fmaf(-q0, G_, Q[0]);  Mr[0] = fmaf(-q0, K_, Mr[0]);             \
    Q[1] = fmaf(-q1, G_, Q[1]);  Mr[1] = fmaf(-q1, K_, Mr[1]);             \
  }

  int4 tg  = *(const int4*)(xp);      // uniform -> s_load_dwordx4
  int4 tgN = *(const int4*)(xp + 4);
  PREF(gA, kA, tg.x);
  PREF(gB, kB, tg.y);

#pragma unroll 1
  for (int n = 0; n < SL / 4; ++n) {
    const int offnn = (n + 2 < SL / 4) ? (n + 2) * 4 : 0;  // uniform, in-bounds
    const int4 tgNN = *(const int4*)(xp + offnn);          // 8 steps ahead
    PREF(gC, kC, tg.z);
    STEP(gA, kA, tg.x);
    PREF(gD, kD, tg.w);
    STEP(gB, kB, tg.y);
    PREF(gA, kA, tgN.x);
    STEP(gC, kC, tg.z);
    PREF(gB, kB, tgN.y);
    STEP(gD, kD, tg.w);
    tg = tgN; tgN = tgNN;
  }
#undef PREF
#undef STEP

  // write M: row = grow + j, col = lane
  float* mp = Mout + ((size_t)bb * H + grow) * H + lane;
  mp[0] = Mr[0];
  mp[H] = Mr[1];
}

// ---------------- Kernel C: attention + readout ----------------
__global__ __launch_bounds__(64) void k_final(
    const int* __restrict__ x, const float* __restrict__ Mws, const float* __restrict__ qtab,
    const float* __restrict__ Wout, const float* __restrict__ bout, float* __restrict__ out)
{
  const int b = blockIdx.x;
  const int i = threadIdx.x;
  __shared__ float Ml[H * 65];
  __shared__ float qs[H];
  __shared__ float attns[H];
  __shared__ float rcs[H];

  const float* Mg = Mws + (size_t)b * H * H;
#pragma unroll
  for (int j4 = 0; j4 < H; j4 += 4) {
    const float4 v = *(const float4*)(Mg + i * H + j4);
    Ml[i * 65 + j4 + 0] = v.x;
    Ml[i * 65 + j4 + 1] = v.y;
    Ml[i * 65 + j4 + 2] = v.z;
    Ml[i * 65 + j4 + 3] = v.w;
  }
  const int tok = x[b * SL + (SL - 1)];
  qs[i] = qtab[tok * H + i];
  __syncthreads();

  float acc = 0.f;
#pragma unroll
  for (int j = 0; j < H; ++j) acc = fmaf(Ml[j * 65 + i], qs[j], acc);
  const float sc = acc * 0.125f;

  float mx = sc;
#pragma unroll
  for (int m = 1; m < 64; m <<= 1) mx = fmaxf(mx, __shfl_xor(mx, m));
  const float e = expf(sc - mx);
  float ssum = e;
#pragma unroll
  for (int m = 1; m < 64; m <<= 1) ssum += __shfl_xor(ssum, m);
  attns[i] = e / ssum;
  __syncthreads();

  float cx = 0.f;
#pragma unroll
  for (int jj = 0; jj < H; ++jj) cx = fmaf(attns[jj], Ml[i * 65 + jj], cx);
  rcs[i] = fmaxf(cx, 0.f);
  __syncthreads();

  float o = bout[i];
#pragma unroll
  for (int j = 0; j < H; ++j) o = fmaf(Wout[i * H + j], rcs[j], o);
  out[b * VOCAB + i] = o;
}

extern "C" void kernel_launch(void* const* d_in, const int* in_sizes, int n_in,
                              void* d_out, int out_size, void* d_ws, size_t ws_size,
                              hipStream_t stream) {
  const int*   x     = (const int*)d_in[0];
  const float* embed = (const float*)d_in[1];
  const float* w1    = (const float*)d_in[2];
  const float* b1    = (const float*)d_in[3];
  const float* w2    = (const float*)d_in[4];
  const float* b2    = (const float*)d_in[5];
  const float* ln_g  = (const float*)d_in[6];
  const float* ln_b  = (const float*)d_in[7];
  const float* Wk    = (const float*)d_in[8];
  const float* Wv    = (const float*)d_in[9];
  const float* Wq    = (const float*)d_in[10];
  const float* Wout  = (const float*)d_in[11];
  const float* bout  = (const float*)d_in[12];

  float* ws   = (float*)d_ws;
  float* Ktab = ws;                 // 4096
  float* Vtab = ws + 4096;          // 4096
  float* qtab = ws + 8192;          // 4096
  float* Mws  = ws + 12288;         // 128*4096

  k_tables<<<dim3(VOCAB), dim3(H), 0, stream>>>(embed, w1, b1, w2, b2, ln_g, ln_b,
                                                Wk, Wv, Wq, Ktab, Vtab, qtab);
  k_scan<<<dim3(4 * NB), dim3(512), 0, stream>>>(x, Ktab, Vtab, Mws);
  k_final<<<dim3(NB), dim3(64), 0, stream>>>(x, Mws, qtab, Wout, bout, (float*)d_out);
}

// Round 13
// 218.877 us; speedup vs baseline: 1.2528x; 1.2528x over previous
//
#include <hip/hip_runtime.h>
#include <hip/hip_bf16.h>

#define VOCAB 64
#define H 64
#define NB 128
#define SL 2048

// ---------------- Kernel A: per-token tables ----------------
__global__ __launch_bounds__(64) void k_tables(
    const float* __restrict__ embed, const float* __restrict__ w1, const float* __restrict__ b1,
    const float* __restrict__ w2, const float* __restrict__ b2,
    const float* __restrict__ ln_g, const float* __restrict__ ln_b,
    const float* __restrict__ Wk, const float* __restrict__ Wv, const float* __restrict__ Wq,
    float* __restrict__ Ktab, float* __restrict__ Vtab, float* __restrict__ qtab)
{
  const int t = blockIdx.x;
  const int i = threadIdx.x;
  __shared__ float h0s[H];
  __shared__ float ff1s[2 * H];
  __shared__ float hs[H];

  h0s[i] = embed[t * H + i];
  __syncthreads();

  const float4* w1v = (const float4*)w1;
  float a0 = b1[i], a1 = b1[i + H];
#pragma unroll
  for (int j4 = 0; j4 < 16; ++j4) {
    const float4 hv = *(const float4*)&h0s[j4 * 4];
    const float4 wa = w1v[i * 16 + j4];
    const float4 wb = w1v[(i + H) * 16 + j4];
    a0 = fmaf(wa.x, hv.x, fmaf(wa.y, hv.y, fmaf(wa.z, hv.z, fmaf(wa.w, hv.w, a0))));
    a1 = fmaf(wb.x, hv.x, fmaf(wb.y, hv.y, fmaf(wb.z, hv.z, fmaf(wb.w, hv.w, a1))));
  }
  ff1s[i] = fmaxf(a0, 0.f);
  ff1s[i + H] = fmaxf(a1, 0.f);
  __syncthreads();

  const float4* w2v = (const float4*)w2;
  float z = h0s[i] + b2[i];
#pragma unroll
  for (int o4 = 0; o4 < 32; ++o4) {
    const float4 fv = *(const float4*)&ff1s[o4 * 4];
    const float4 wv = w2v[i * 32 + o4];
    z = fmaf(wv.x, fv.x, fmaf(wv.y, fv.y, fmaf(wv.z, fv.z, fmaf(wv.w, fv.w, z))));
  }

  float s = z;
#pragma unroll
  for (int m = 1; m < 64; m <<= 1) s += __shfl_xor(s, m);
  const float mu = s * (1.f / 64.f);
  const float d = z - mu;
  float s2 = d * d;
#pragma unroll
  for (int m = 1; m < 64; m <<= 1) s2 += __shfl_xor(s2, m);
  const float var = s2 * (1.f / 64.f);
  const float hv2 = d * rsqrtf(var + 1e-5f) * ln_g[i] + ln_b[i];
  hs[i] = hv2;
  __syncthreads();

  const float4* wkv = (const float4*)Wk;
  const float4* wvv = (const float4*)Wv;
  const float4* wqv = (const float4*)Wq;
  float kk = 0.f, vv = 0.f, qq = 0.f;
#pragma unroll
  for (int j4 = 0; j4 < 16; ++j4) {
    const float4 hj = *(const float4*)&hs[j4 * 4];
    const float4 ak = wkv[i * 16 + j4];
    const float4 av = wvv[i * 16 + j4];
    const float4 aq = wqv[i * 16 + j4];
    kk = fmaf(ak.x, hj.x, fmaf(ak.y, hj.y, fmaf(ak.z, hj.z, fmaf(ak.w, hj.w, kk))));
    vv = fmaf(av.x, hj.x, fmaf(av.y, hj.y, fmaf(av.z, hj.z, fmaf(av.w, hj.w, vv))));
    qq = fmaf(aq.x, hj.x, fmaf(aq.y, hj.y, fmaf(aq.z, hj.z, fmaf(aq.w, hj.w, qq))));
  }
  float n2 = kk * kk;
#pragma unroll
  for (int m = 1; m < 64; m <<= 1) n2 += __shfl_xor(n2, m);
  const float inv = 1.f / fmaxf(sqrtf(n2), 1e-12f);
  Ktab[t * H + i] = kk * inv;
  Vtab[t * H + i] = vv;
  qtab[t * H + i] = qq;
}

// ---------------- Kernel A2: interleaved {Gram, K} table ----------------
// GKtab[a][b] = { dot(K[a],K[b]), K[a][b] }  (float2, coalesced writes)
__global__ __launch_bounds__(64) void k_gram(const float* __restrict__ Ktab,
                                             float2* __restrict__ GKtab)
{
  const int a = blockIdx.x;
  const int b = threadIdx.x;
  __shared__ float row[H];
  row[b] = Ktab[a * H + b];
  __syncthreads();
  const float4* kb = (const float4*)(Ktab + b * H);
  float acc = 0.f;
#pragma unroll
  for (int q = 0; q < 16; ++q) {
    const float4 rb = kb[q];
    const float4 ra = *(const float4*)&row[q * 4];
    acc = fmaf(ra.x, rb.x, fmaf(ra.y, rb.y, fmaf(ra.z, rb.z, fmaf(ra.w, rb.w, acc))));
  }
  float2 o; o.x = acc; o.y = row[b];
  GKtab[a * H + b] = o;
}

// ---------------- Kernel B: Q-cache delta-rule scan ----------------
// State per batch: M (64x64) and Q = M.Ktab^T - V^T. Step with token a:
//   dl_r = -Q[r][a]  (v_readlane);  Q += dl (x) G[a,:];  M += dl (x) K[a,:].
// Decomposition: 4 blocks/batch x 16 rows; block 512 = 8 waves x 2 rows.
// LDS = 32KB exactly (only the precomputed {G,K} table) so 2 blocks/CU
// co-reside -> 4 independent wave-chains/SIMD cover rdl/fma/DS latency.
// (round 12: 66048B LDS -> 2x132KB > 128KB usable -> blocks serialized.)
__device__ __forceinline__ float rdl(float v, int sl) {
  return __int_as_float(__builtin_amdgcn_readlane(__float_as_int(v), sl));
}

__global__ __launch_bounds__(512) void k_scan(
    const int* __restrict__ x, const float2* __restrict__ GKtab,
    const float* __restrict__ Vtab, float* __restrict__ Mout)
{
  const int bb = blockIdx.x >> 2;
  const int quarter = blockIdx.x & 3;
  const int tid = threadIdx.x;   // 0..511
  const int lane = tid & 63;
  const int wave = tid >> 6;     // 0..7
  const int grow = quarter * 16 + wave * 2;  // global row base (2 rows/wave)

  __shared__ float2 GKs[VOCAB * H];  // 32768 B

  // ---- stage {G,K} (coalesced float2) ----
#pragma unroll
  for (int u = 0; u < 8; ++u) GKs[u * 512 + tid] = GKtab[u * 512 + tid];
  __syncthreads();

  // ---- init Q = -V^T slice (P=0), M = 0; one-time global gather ----
  float Q[2], Mr[2];
  Q[0] = -Vtab[lane * H + grow + 0];
  Q[1] = -Vtab[lane * H + grow + 1];
  Mr[0] = 0.f; Mr[1] = 0.f;

  const int* __restrict__ xp = x + bb * SL;  // block-uniform -> scalar loads

  float gA, kA, gB, kB, gC, kC, gD, kD;

#define PREF(G_, K_, a_)                                                   \
  {                                                                        \
    const float2 gk = GKs[(a_) * H + lane];                                \
    G_ = gk.x; K_ = gk.y;                                                  \
  }

#define STEP(G_, K_, a_)                                                   \
  {                                                                        \
    const float q0 = rdl(Q[0], a_);                                        \
    const float q1 = rdl(Q[1], a_);                                        \
    Q[0] = fmaf(-q0, G_, Q[0]);  Mr[0] = fmaf(-q0, K_, Mr[0]);             \
    Q[1] = fmaf(-q1, G_, Q[1]);  Mr[1] = fmaf(-q1, K_, Mr[1]);             \
  }

  int4 tg  = *(const int4*)(xp);      // uniform -> s_load_dwordx4
  int4 tgN = *(const int4*)(xp + 4);
  PREF(gA, kA, tg.x);
  PREF(gB, kB, tg.y);

#pragma unroll 1
  for (int n = 0; n < SL / 4; ++n) {
    const int offnn = (n + 2 < SL / 4) ? (n + 2) * 4 : 0;  // uniform, in-bounds
    const int4 tgNN = *(const int4*)(xp + offnn);          // 8 steps ahead
    PREF(gC, kC, tg.z);
    STEP(gA, kA, tg.x);
    PREF(gD, kD, tg.w);
    STEP(gB, kB, tg.y);
    PREF(gA, kA, tgN.x);
    STEP(gC, kC, tg.z);
    PREF(gB, kB, tgN.y);
    STEP(gD, kD, tg.w);
    tg = tgN; tgN = tgNN;
  }
#undef PREF
#undef STEP

  // write M: row = grow + j, col = lane
  float* mp = Mout + ((size_t)bb * H + grow) * H + lane;
  mp[0] = Mr[0];
  mp[H] = Mr[1];
}

// ---------------- Kernel C: attention + readout ----------------
__global__ __launch_bounds__(64) void k_final(
    const int* __restrict__ x, const float* __restrict__ Mws, const float* __restrict__ qtab,
    const float* __restrict__ Wout, const float* __restrict__ bout, float* __restrict__ out)
{
  const int b = blockIdx.x;
  const int i = threadIdx.x;
  __shared__ float Ml[H * 65];
  __shared__ float qs[H];
  __shared__ float attns[H];
  __shared__ float rcs[H];

  const float* Mg = Mws + (size_t)b * H * H;
#pragma unroll
  for (int j4 = 0; j4 < H; j4 += 4) {
    const float4 v = *(const float4*)(Mg + i * H + j4);
    Ml[i * 65 + j4 + 0] = v.x;
    Ml[i * 65 + j4 + 1] = v.y;
    Ml[i * 65 + j4 + 2] = v.z;
    Ml[i * 65 + j4 + 3] = v.w;
  }
  const int tok = x[b * SL + (SL - 1)];
  qs[i] = qtab[tok * H + i];
  __syncthreads();

  float acc = 0.f;
#pragma unroll
  for (int j = 0; j < H; ++j) acc = fmaf(Ml[j * 65 + i], qs[j], acc);
  const float sc = acc * 0.125f;

  float mx = sc;
#pragma unroll
  for (int m = 1; m < 64; m <<= 1) mx = fmaxf(mx, __shfl_xor(mx, m));
  const float e = expf(sc - mx);
  float ssum = e;
#pragma unroll
  for (int m = 1; m < 64; m <<= 1) ssum += __shfl_xor(ssum, m);
  attns[i] = e / ssum;
  __syncthreads();

  float cx = 0.f;
#pragma unroll
  for (int jj = 0; jj < H; ++jj) cx = fmaf(attns[jj], Ml[i * 65 + jj], cx);
  rcs[i] = fmaxf(cx, 0.f);
  __syncthreads();

  float o = bout[i];
#pragma unroll
  for (int j = 0; j < H; ++j) o = fmaf(Wout[i * H + j], rcs[j], o);
  out[b * VOCAB + i] = o;
}

extern "C" void kernel_launch(void* const* d_in, const int* in_sizes, int n_in,
                              void* d_out, int out_size, void* d_ws, size_t ws_size,
                              hipStream_t stream) {
  const int*   x     = (const int*)d_in[0];
  const float* embed = (const float*)d_in[1];
  const float* w1    = (const float*)d_in[2];
  const float* b1    = (const float*)d_in[3];
  const float* w2    = (const float*)d_in[4];
  const float* b2    = (const float*)d_in[5];
  const float* ln_g  = (const float*)d_in[6];
  const float* ln_b  = (const float*)d_in[7];
  const float* Wk    = (const float*)d_in[8];
  const float* Wv    = (const float*)d_in[9];
  const float* Wq    = (const float*)d_in[10];
  const float* Wout  = (const float*)d_in[11];
  const float* bout  = (const float*)d_in[12];

  float* ws   = (float*)d_ws;
  float* Ktab = ws;                 // 4096
  float* Vtab = ws + 4096;          // 4096
  float* qtab = ws + 8192;          // 4096
  float2* GKtab = (float2*)(ws + 12288);  // 4096 float2 = 8192 floats
  float* Mws  = ws + 20480;         // 128*4096

  k_tables<<<dim3(VOCAB), dim3(H), 0, stream>>>(embed, w1, b1, w2, b2, ln_g, ln_b,
                                                Wk, Wv, Wq, Ktab, Vtab, qtab);
  k_gram<<<dim3(VOCAB), dim3(H), 0, stream>>>(Ktab, GKtab);
  k_scan<<<dim3(4 * NB), dim3(512), 0, stream>>>(x, GKtab, Vtab, Mws);
  k_final<<<dim3(NB), dim3(64), 0, stream>>>(x, Mws, qtab, Wout, bout, (float*)d_out);
}